// Round 3
// baseline (474.641 us; speedup 1.0000x reference)
//
#include <hip/hip_runtime.h>
#include <hip/hip_bf16.h>

#define LNUM 4
#define DIM  512
#define SS   256

typedef unsigned short ushort_t;
typedef __attribute__((ext_vector_type(8))) short bf16x8;
typedef __attribute__((ext_vector_type(4))) float f32x4;

#define VWAIT(n) asm volatile("s_waitcnt vmcnt(" #n ")" ::: "memory")
__device__ __forceinline__ void bar() { __builtin_amdgcn_s_barrier(); }

__device__ __forceinline__ ushort_t f2b(float f) {
  union { float f; unsigned u; } x; x.f = f;
  unsigned r = x.u + 0x7FFFu + ((x.u >> 16) & 1u);
  return (ushort_t)(r >> 16);
}

__device__ __forceinline__ void gload16(const void* g, void* s) {
  __builtin_amdgcn_global_load_lds((const __attribute__((address_space(1))) void*)g,
                                   (__attribute__((address_space(3))) void*)s, 16, 0, 0);
}

// ---------------------------------------------------------------------------
// C = A * B^T, 3-buffer depth-2 pipeline, counted vmcnt, raw barriers.
// EPI 0: outB = bf16(acc + bias) [relu opt]
// EPI 2: outF[kz partial] = acc + bias(kz==0)   (plain fp32 store)
// EPI 3: fused QKV routing; V segment written directly transposed to vT
// ---------------------------------------------------------------------------
template<int TM, int TN, int EPI>
__global__ __launch_bounds__(256, 2)
void gemm_bt(const ushort_t* __restrict__ A, const ushort_t* __restrict__ B,
             const float* __restrict__ bias, const float* __restrict__ bias2,
             const float* __restrict__ bias3,
             ushort_t* __restrict__ outB, ushort_t* __restrict__ outB2,
             ushort_t* __restrict__ outB3, float* __restrict__ outF,
             int K, int lda, int ldb, int ldc, int nkz, int relu)
{
  constexpr int CA = TM / 32, CB = TN / 32, SN = CA + CB;
  constexpr int WM = TM / 32, WN = TN / 32;
  __shared__ ushort_t As[3 * TM * 64];
  __shared__ ushort_t Bs[3 * TN * 64];
  const int tid = threadIdx.x, lane = tid & 63, wid = tid >> 6;
  const int wm = wid >> 1, wn = wid & 1;
  const int kz = blockIdx.z, Kz = K / nkz, k0 = kz * Kz, nt = Kz >> 6;

  const ushort_t* Ab = A + (long)blockIdx.y * TM * lda + k0;
  const ushort_t* Bb = B + (long)blockIdx.x * TN * ldb + k0;

  const ushort_t* srcA[CA]; ushort_t* ldsA[CA];
  const ushort_t* srcB[CB]; ushort_t* ldsB[CB];
#pragma unroll
  for (int c = 0; c < CA; ++c) {
    int off = c * 4096 + tid * 16;
    int row = off >> 7;
    int scol = ((off & 127) ^ ((row & 7) << 4)) >> 1;
    srcA[c] = Ab + (long)row * lda + scol;
    ldsA[c] = As + c * 2048 + wid * 512;
  }
#pragma unroll
  for (int c = 0; c < CB; ++c) {
    int off = c * 4096 + tid * 16;
    int row = off >> 7;
    int scol = ((off & 127) ^ ((row & 7) << 4)) >> 1;
    srcB[c] = Bb + (long)row * ldb + scol;
    ldsB[c] = Bs + c * 2048 + wid * 512;
  }

  f32x4 acc[WM][WN] = {};

  auto STAGE = [&](int buf, int t) {
#pragma unroll
    for (int c = 0; c < CA; ++c) gload16(srcA[c] + t * 64, ldsA[c] + buf * TM * 64);
#pragma unroll
    for (int c = 0; c < CB; ++c) gload16(srcB[c] + t * 64, ldsB[c] + buf * TN * 64);
  };

  STAGE(0, 0);
  STAGE(1, 1);
  for (int t = 0; t < nt; ++t) {
    if (t < nt - 1) { if constexpr (SN == 6) VWAIT(6); else VWAIT(4); }
    else VWAIT(0);
    bar();
    if (t + 2 < nt) STAGE((t + 2) % 3, t + 2);
    const int buf = t % 3;
#pragma unroll
    for (int ks = 0; ks < 2; ++ks) {
      const int kb = ks * 64 + ((lane >> 4) << 4);
      bf16x8 af[WM], bfr[WN];
#pragma unroll
      for (int f = 0; f < WM; ++f) {
        int ra = wm * (TM / 2) + f * 16 + (lane & 15);
        af[f] = *(const bf16x8*)((const char*)As + buf * TM * 128 + ra * 128 + (kb ^ ((ra & 7) << 4)));
      }
#pragma unroll
      for (int g = 0; g < WN; ++g) {
        int rb = wn * (TN / 2) + g * 16 + (lane & 15);
        bfr[g] = *(const bf16x8*)((const char*)Bs + buf * TN * 128 + rb * 128 + (kb ^ ((rb & 7) << 4)));
      }
#pragma unroll
      for (int i = 0; i < WM; ++i)
#pragma unroll
        for (int j = 0; j < WN; ++j)
          acc[i][j] = __builtin_amdgcn_mfma_f32_16x16x32_bf16(af[i], bfr[j], acc[i][j], 0, 0, 0);
    }
  }

  const int row0 = blockIdx.y * TM + wm * (TM / 2) + ((lane >> 4) << 2);
  int col0 = blockIdx.x * TN + wn * (TN / 2) + (lane & 15);
  const float* bsel = bias;
  ushort_t* osel = outB;
  int seg = 0;
  if (EPI == 3) {
    seg = (blockIdx.x * TN) >> 11;
    if (seg == 1) { bsel = bias2; osel = outB2; }
    else if (seg == 2) { bsel = bias3; }
    col0 -= seg * 2048;
  }
#pragma unroll
  for (int i = 0; i < WM; ++i) {
#pragma unroll
    for (int j = 0; j < WN; ++j) {
      const int col = col0 + j * 16;
      float bv;
      if (EPI == 2) bv = (kz == 0) ? bias[col] : 0.f;
      else          bv = bsel[col];
#pragma unroll
      for (int r = 0; r < 4; ++r) {
        const int row = row0 + i * 16 + r;
        float v = acc[i][j][r] + bv;
        if (EPI == 2) {
          outF[(long)kz * 1048576 + (long)row * ldc + col] = v;
        } else if (EPI == 3 && seg == 2) {
          // vT[bh][dk][s]: b=row>>8, s=row&255, h=col>>8, dk=col&255
          int bh = ((row >> 8) << 3) + (col >> 8);
          outB3[((long)bh << 16) + (long)(col & 255) * 256 + (row & 255)] = f2b(v);
        } else {
          if (relu) v = fmaxf(v, 0.f);
          osel[(long)row * ldc + col] = f2b(v);
        }
      }
    }
  }
}

// ---------------------------------------------------------------------------
// Fused flash attention, 10-phase counted-vmcnt pipeline, depth-2 prefetch.
// Block: (q-tile of 64, b*8+h). Qs (32KB) reused as P after QK phase.
// ---------------------------------------------------------------------------
__global__ __launch_bounds__(256)
void attn_k(const ushort_t* __restrict__ qb, const ushort_t* __restrict__ kbf,
            const ushort_t* __restrict__ vT, const int* __restrict__ attnm,
            ushort_t* __restrict__ ao)
{
  __shared__ ushort_t Qs[64 * 256];        // 32KB; becomes P after QK
  __shared__ ushort_t KV[3][64 * 256];     // 96KB
  __shared__ int smask[256];
  const int qt = blockIdx.x, bh = blockIdx.y, b = bh >> 3, h = bh & 7;
  const int tid = threadIdx.x, lane = tid & 63, wid = tid >> 6;

  smask[tid] = attnm[b * 256 + tid];
  VWAIT(0);   // drain mask load so stage counting is exact

  int srow[8], scol[8];
#pragma unroll
  for (int c = 0; c < 8; ++c) {
    int off = c * 4096 + tid * 16;
    srow[c] = off >> 9;
    scol[c] = ((off & 511) ^ ((srow[c] & 7) << 4)) >> 1;
  }

#define STQ() do { _Pragma("unroll") for (int c = 0; c < 8; ++c) \
  gload16(qb + (long)(b * 256 + qt * 64 + srow[c]) * 2048 + h * 256 + scol[c], Qs + c * 2048 + wid * 512); } while (0)
#define STK(KC, DST) do { _Pragma("unroll") for (int c = 0; c < 8; ++c) \
  gload16(kbf + (long)(b * 256 + (KC) * 64 + srow[c]) * 2048 + h * 256 + scol[c], (DST) + c * 2048 + wid * 512); } while (0)
#define STV(VC, DST) do { _Pragma("unroll") for (int c = 0; c < 8; ++c) \
  gload16(vT + ((long)bh << 16) + (long)((VC) * 64 + srow[c]) * 256 + scol[c], (DST) + c * 2048 + wid * 512); } while (0)

  f32x4 accs[16] = {};
  f32x4 acco[4][4] = {};

#define QKC(IDX, KVB) do { _Pragma("unroll") \
  for (int ks = 0; ks < 8; ++ks) { \
    const int kb = ks * 64 + ((lane >> 4) << 4); \
    const int ra = wid * 16 + (lane & 15); \
    bf16x8 aq = *(const bf16x8*)((const char*)Qs + ra * 512 + (kb ^ ((ra & 7) << 4))); \
    _Pragma("unroll") \
    for (int j = 0; j < 4; ++j) { \
      const int rb = j * 16 + (lane & 15); \
      bf16x8 bk_ = *(const bf16x8*)((const char*)(KVB) + rb * 512 + (kb ^ ((rb & 7) << 4))); \
      accs[(IDX) * 4 + j] = __builtin_amdgcn_mfma_f32_16x16x32_bf16(aq, bk_, accs[(IDX) * 4 + j], 0, 0, 0); \
    } \
  } } while (0)

#define PVC(VC, KVB) do { _Pragma("unroll") \
  for (int ks = 0; ks < 8; ++ks) { \
    const int kb = ks * 64 + ((lane >> 4) << 4); \
    const int ra = wid * 16 + (lane & 15); \
    bf16x8 pa = *(const bf16x8*)((const char*)Qs + ra * 512 + (kb ^ ((ra & 7) << 4))); \
    _Pragma("unroll") \
    for (int j = 0; j < 4; ++j) { \
      const int rb = j * 16 + (lane & 15); \
      bf16x8 bv_ = *(const bf16x8*)((const char*)(KVB) + rb * 512 + (kb ^ ((rb & 7) << 4))); \
      acco[VC][j] = __builtin_amdgcn_mfma_f32_16x16x32_bf16(pa, bv_, acco[VC][j], 0, 0, 0); \
    } \
  } } while (0)

  // prologue: Q, K0, K1 in flight (24)
  STQ(); STK(0, KV[0]); STK(1, KV[1]);

  VWAIT(16); bar(); STK(2, KV[2]); QKC(0, KV[0]);   // wait Q,K0
  VWAIT(8);  bar(); STK(3, KV[0]); QKC(1, KV[1]);   // wait K1
  VWAIT(8);  bar(); STV(0, KV[1]); QKC(2, KV[2]);   // wait K2
  VWAIT(8);  bar(); STV(1, KV[2]); QKC(3, KV[0]);   // wait K3

  bar();              // all waves done with Qs(Q) and KV[0](K3)
  STV(2, KV[0]);      // outstanding: V0,V1,V2 = 24

  // softmax over 256 keys per q-row; lane holds 16 cols x 4 rows
  {
    float mr[4] = {-3e38f, -3e38f, -3e38f, -3e38f}, sr[4] = {};
#pragma unroll
    for (int jj = 0; jj < 16; ++jj) {
      int key = jj * 16 + (lane & 15);
      bool mk = smask[key] != 0;
#pragma unroll
      for (int r = 0; r < 4; ++r) {
        float s = mk ? -1e9f : accs[jj][r] * 0.0625f;
        accs[jj][r] = s;
        mr[r] = fmaxf(mr[r], s);
      }
    }
#pragma unroll
    for (int o = 1; o < 16; o <<= 1)
#pragma unroll
      for (int r = 0; r < 4; ++r) mr[r] = fmaxf(mr[r], __shfl_xor(mr[r], o, 64));
#pragma unroll
    for (int jj = 0; jj < 16; ++jj)
#pragma unroll
      for (int r = 0; r < 4; ++r) {
        float e = __expf(accs[jj][r] - mr[r]);
        accs[jj][r] = e;
        sr[r] += e;
      }
#pragma unroll
    for (int o = 1; o < 16; o <<= 1)
#pragma unroll
      for (int r = 0; r < 4; ++r) sr[r] += __shfl_xor(sr[r], o, 64);
#pragma unroll
    for (int r = 0; r < 4; ++r) sr[r] = 1.f / sr[r];
    // P -> Qs (own wave's rows only; no barrier needed)
#pragma unroll
    for (int jj = 0; jj < 16; ++jj)
#pragma unroll
      for (int r = 0; r < 4; ++r) {
        int prow = wid * 16 + ((lane >> 4) << 2) + r;
        int cb = (jj * 16 + (lane & 15)) * 2;
        *(ushort_t*)((char*)Qs + prow * 512 + (cb ^ ((prow & 7) << 4))) = f2b(accs[jj][r] * sr[r]);
      }
  }

  VWAIT(16); bar();                 PVC(0, KV[1]);  // wait V0
  VWAIT(8);  bar(); STV(3, KV[1]); PVC(1, KV[2]);   // wait V1
  VWAIT(8);  bar();                 PVC(2, KV[0]);  // wait V2
  VWAIT(0);  bar();                 PVC(3, KV[1]);  // wait V3

#pragma unroll
  for (int vc = 0; vc < 4; ++vc)
#pragma unroll
    for (int j = 0; j < 4; ++j)
#pragma unroll
      for (int r = 0; r < 4; ++r) {
        int q = qt * 64 + wid * 16 + ((lane >> 4) << 2) + r;
        int dk = vc * 64 + j * 16 + (lane & 15);
        ao[(long)(b * 256 + q) * 2048 + h * 256 + dk] = f2b(acco[vc][j][r]);
      }
#undef STQ
#undef STK
#undef STV
#undef QKC
#undef PVC
}

// x = data*sqrt(D) + pe + seg_emb[view_idx*S]
__global__ __launch_bounds__(256)
void build_x(const float* __restrict__ data, const float* __restrict__ seg,
             const int* __restrict__ viewp, float* __restrict__ x)
{
  int i = blockIdx.x * 256 + threadIdx.x;
  int d = i & 511;
  int s = (i >> 9) & 255;
  float ang = (float)s * exp2f((float)d * -0.03125f);
  float pe = (d & 1) ? cosf(ang) : sinf(ang);
  int vrow = viewp[0] * SS;
  x[i] = data[i] * 22.627416997969522f + pe + seg[vrow * DIM + d];
}

// LayerNorm with optional fused residual: xr = x + p0 + p1 (write back to xout),
// then normalize (unbiased var, eps on std). outB: bf16 out; outF: fp32 out.
__global__ __launch_bounds__(256)
void lnorm_k(const float* __restrict__ x, const float* __restrict__ p0,
             const float* __restrict__ p1, float* __restrict__ xout,
             const float* __restrict__ alpha, const float* __restrict__ beta,
             ushort_t* __restrict__ outB, float* __restrict__ outF)
{
  const int row = blockIdx.x, tid = threadIdx.x;
  const long base = (long)row * DIM;
  float2 v = ((const float2*)(x + base))[tid];
  if (p0) {
    float2 a = ((const float2*)(p0 + base))[tid];
    float2 c = ((const float2*)(p1 + base))[tid];
    v.x += a.x + c.x; v.y += a.y + c.y;
    ((float2*)(xout + base))[tid] = v;
  }
  float s = v.x + v.y;
#pragma unroll
  for (int o = 32; o; o >>= 1) s += __shfl_xor(s, o, 64);
  __shared__ float rs[4], rq[4];
  if ((tid & 63) == 0) rs[tid >> 6] = s;
  __syncthreads();
  const float mu = (rs[0] + rs[1] + rs[2] + rs[3]) * (1.f / 512.f);
  const float dx = v.x - mu, dy = v.y - mu;
  float q = dx * dx + dy * dy;
#pragma unroll
  for (int o = 32; o; o >>= 1) q += __shfl_xor(q, o, 64);
  if ((tid & 63) == 0) rq[tid >> 6] = q;
  __syncthreads();
  const float var = (rq[0] + rq[1] + rq[2] + rq[3]) * (1.f / 511.f);
  const float rstd = 1.f / (sqrtf(var) + 1e-6f);
  const int d0 = tid * 2;
  const float o0 = alpha[d0] * dx * rstd + beta[d0];
  const float o1 = alpha[d0 + 1] * dy * rstd + beta[d0 + 1];
  if (outB) { outB[base + d0] = f2b(o0); outB[base + d0 + 1] = f2b(o1); }
  else      { outF[base + d0] = o0;      outF[base + d0 + 1] = o1; }
}

// fp32 [R,C] -> bf16 [C,R], per-z with output z-stride (elements)
__global__ __launch_bounds__(256)
void wtrans(const float* __restrict__ in, ushort_t* __restrict__ out,
            int R, int C, long ozs)
{
  __shared__ float t[32][33];
  const int z = blockIdx.z;
  const long zi = (long)z * R * C, zo = (long)z * ozs;
  const int c0 = blockIdx.x * 32, r0 = blockIdx.y * 32;
  const int tx = threadIdx.x & 31, ty = threadIdx.x >> 5;
#pragma unroll
  for (int i = 0; i < 4; ++i) t[ty + i * 8][tx] = in[zi + (long)(r0 + ty + i * 8) * C + c0 + tx];
  __syncthreads();
#pragma unroll
  for (int i = 0; i < 4; ++i) out[zo + (long)(c0 + ty + i * 8) * R + r0 + tx] = f2b(t[tx][ty + i * 8]);
}

extern "C" void kernel_launch(void* const* d_in, const int* in_sizes, int n_in,
                              void* d_out, int out_size, void* d_ws, size_t ws_size,
                              hipStream_t stream)
{
  const float* data  = (const float*)d_in[0];
  const int*   attnm = (const int*)d_in[1];
  const int*   viewp = (const int*)d_in[2];
  const float* seg   = (const float*)d_in[3];
  const float* Wq    = (const float*)d_in[4];
  const float* bq    = (const float*)d_in[5];
  const float* Wk    = (const float*)d_in[6];
  const float* bk    = (const float*)d_in[7];
  const float* Wv    = (const float*)d_in[8];
  const float* bv    = (const float*)d_in[9];
  const float* Wo    = (const float*)d_in[10];
  const float* bo    = (const float*)d_in[11];
  const float* W1    = (const float*)d_in[12];
  const float* b1    = (const float*)d_in[13];
  const float* W2    = (const float*)d_in[14];
  const float* b2    = (const float*)d_in[15];
  const float* al1   = (const float*)d_in[16];
  const float* be1   = (const float*)d_in[17];
  const float* al2   = (const float*)d_in[18];
  const float* be2   = (const float*)d_in[19];
  const float* alf   = (const float*)d_in[20];
  const float* bef   = (const float*)d_in[21];

  char* w = (char*)d_ws;
  const size_t MB = 1024 * 1024;
  ushort_t* qkvW = (ushort_t*)(w + 0 * MB);   // [L][6144][512] bf16
  ushort_t* WoT  = (ushort_t*)(w + 24 * MB);  // [L][512][2048]
  ushort_t* W1T  = (ushort_t*)(w + 32 * MB);  // [L][2048][512]
  ushort_t* W2T  = (ushort_t*)(w + 40 * MB);  // [L][512][2048]
  float*    x    = (float*)   (w + 48 * MB);  // [2048][512] fp32
  ushort_t* x2   = (ushort_t*)(w + 52 * MB);  // [2048][512] bf16
  ushort_t* qb   = (ushort_t*)(w + 54 * MB);  // [2048][2048] bf16
  ushort_t* kbf  = (ushort_t*)(w + 62 * MB);
  ushort_t* vT   = (ushort_t*)(w + 70 * MB);  // [64][256][256]
  ushort_t* ao   = (ushort_t*)(w + 78 * MB);  // [2048][2048]
  ushort_t* ffh  = (ushort_t*)(w + 86 * MB);  // [2048][2048]
  float*    pA   = (float*)   (w + 94 * MB);  // [2048][512] fp32 partial kz=0
  float*    pB   = (float*)   (w + 98 * MB);  // [2048][512] fp32 partial kz=1 (end 102MB)

  dim3 blk(256);
  const long QKV_L = 6144L * 512;
  wtrans<<<dim3(64, 16, 4), blk, 0, stream>>>(Wq, qkvW + 0 * 2048 * 512, 512, 2048, QKV_L);
  wtrans<<<dim3(64, 16, 4), blk, 0, stream>>>(Wk, qkvW + 1 * 2048 * 512, 512, 2048, QKV_L);
  wtrans<<<dim3(64, 16, 4), blk, 0, stream>>>(Wv, qkvW + 2 * 2048 * 512, 512, 2048, QKV_L);
  wtrans<<<dim3(16, 64, 4), blk, 0, stream>>>(Wo, WoT, 2048, 512, 512L * 2048);
  wtrans<<<dim3(64, 16, 4), blk, 0, stream>>>(W1, W1T, 512, 2048, 2048L * 512);
  wtrans<<<dim3(16, 64, 4), blk, 0, stream>>>(W2, W2T, 2048, 512, 512L * 2048);
  build_x<<<4096, blk, 0, stream>>>(data, seg, viewp, x);

  for (int i = 0; i < LNUM; ++i) {
    if (i == 0)
      lnorm_k<<<2048, blk, 0, stream>>>(x, nullptr, nullptr, nullptr,
                                        al1, be1, x2, nullptr);
    // fused QKV: [2048,512] x [6144,512]^T ; V written transposed to vT
    gemm_bt<128, 64, 3><<<dim3(96, 16, 1), blk, 0, stream>>>(
        x2, qkvW + (long)i * QKV_L, bq + i * 2048, bk + i * 2048, bv + i * 2048,
        qb, kbf, vT, nullptr, 512, 512, 512, 2048, 1, 0);
    attn_k<<<dim3(4, 64), blk, 0, stream>>>(qb, kbf, vT, attnm, ao);
    // Wo: [2048,2048] x [512,2048]^T, split-K=2 -> pA,pB
    gemm_bt<64, 64, 2><<<dim3(8, 32, 2), blk, 0, stream>>>(
        ao, WoT + (long)i * 512 * 2048, bo + i * 512, nullptr, nullptr,
        nullptr, nullptr, nullptr, pA, 2048, 2048, 2048, 512, 2, 0);
    lnorm_k<<<2048, blk, 0, stream>>>(x, pA, pB, x, al2 + i * 512, be2 + i * 512, x2, nullptr);
    // FF1: [2048,512] x [2048,512]^T, relu
    gemm_bt<128, 64, 0><<<dim3(32, 16, 1), blk, 0, stream>>>(
        x2, W1T + (long)i * 2048 * 512, b1 + i * 2048, nullptr, nullptr,
        ffh, nullptr, nullptr, nullptr, 512, 512, 512, 2048, 1, 1);
    // FF2: [2048,2048] x [512,2048]^T, split-K=2 -> pA,pB
    gemm_bt<64, 64, 2><<<dim3(8, 32, 2), blk, 0, stream>>>(
        ffh, W2T + (long)i * 512 * 2048, b2 + i * 512, nullptr, nullptr,
        nullptr, nullptr, nullptr, pA, 2048, 2048, 2048, 512, 2, 0);
    if (i < LNUM - 1)
      lnorm_k<<<2048, blk, 0, stream>>>(x, pA, pB, x, al1 + (i + 1) * 512, be1 + (i + 1) * 512, x2, nullptr);
    else
      lnorm_k<<<2048, blk, 0, stream>>>(x, pA, pB, x, alf, bef, nullptr, (float*)d_out);
  }
}

// Round 4
// 451.853 us; speedup vs baseline: 1.0504x; 1.0504x over previous
//
#include <hip/hip_runtime.h>
#include <hip/hip_bf16.h>

#define LNUM 4
#define DIM  512
#define SS   256

typedef unsigned short ushort_t;
typedef __attribute__((ext_vector_type(8))) short bf16x8;
typedef __attribute__((ext_vector_type(4))) float f32x4;
typedef __attribute__((ext_vector_type(8))) unsigned short u16x8;

#define VWAIT(n) asm volatile("s_waitcnt vmcnt(" #n ")" ::: "memory")
__device__ __forceinline__ void bar() { __builtin_amdgcn_s_barrier(); }

__device__ __forceinline__ ushort_t f2b(float f) {
  union { float f; unsigned u; } x; x.f = f;
  unsigned r = x.u + 0x7FFFu + ((x.u >> 16) & 1u);
  return (ushort_t)(r >> 16);
}

__device__ __forceinline__ void gload16(const void* g, void* s) {
  __builtin_amdgcn_global_load_lds((const __attribute__((address_space(1))) void*)g,
                                   (__attribute__((address_space(3))) void*)s, 16, 0, 0);
}

// ---------------------------------------------------------------------------
// C = A * B^T, 3-buffer depth-2 pipeline, counted vmcnt, raw barriers.
// EPI 0: outB = bf16(acc + bias) [relu opt]
// EPI 2: outF[kz partial] = acc + bias(kz==0)   (plain fp32 store)
// EPI 3: fused QKV routing; V segment repacked via LDS -> vT coalesced
// ---------------------------------------------------------------------------
template<int TM, int TN, int EPI>
__global__ __launch_bounds__(256, 2)
void gemm_bt(const ushort_t* __restrict__ A, const ushort_t* __restrict__ B,
             const float* __restrict__ bias, const float* __restrict__ bias2,
             const float* __restrict__ bias3,
             ushort_t* __restrict__ outB, ushort_t* __restrict__ outB2,
             ushort_t* __restrict__ outB3, float* __restrict__ outF,
             int K, int lda, int ldb, int ldc, int nkz, int relu)
{
  constexpr int CA = TM / 32, CB = TN / 32, SN = CA + CB;
  constexpr int WM = TM / 32, WN = TN / 32;
  __shared__ ushort_t As[3 * TM * 64];
  __shared__ ushort_t Bs[3 * TN * 64];
  const int tid = threadIdx.x, lane = tid & 63, wid = tid >> 6;
  const int wm = wid >> 1, wn = wid & 1;
  const int kz = blockIdx.z, Kz = K / nkz, k0 = kz * Kz, nt = Kz >> 6;

  const ushort_t* Ab = A + (long)blockIdx.y * TM * lda + k0;
  const ushort_t* Bb = B + (long)blockIdx.x * TN * ldb + k0;

  const ushort_t* srcA[CA]; ushort_t* ldsA[CA];
  const ushort_t* srcB[CB]; ushort_t* ldsB[CB];
#pragma unroll
  for (int c = 0; c < CA; ++c) {
    int off = c * 4096 + tid * 16;
    int row = off >> 7;
    int scol = ((off & 127) ^ ((row & 7) << 4)) >> 1;
    srcA[c] = Ab + (long)row * lda + scol;
    ldsA[c] = As + c * 2048 + wid * 512;
  }
#pragma unroll
  for (int c = 0; c < CB; ++c) {
    int off = c * 4096 + tid * 16;
    int row = off >> 7;
    int scol = ((off & 127) ^ ((row & 7) << 4)) >> 1;
    srcB[c] = Bb + (long)row * ldb + scol;
    ldsB[c] = Bs + c * 2048 + wid * 512;
  }

  f32x4 acc[WM][WN] = {};

  auto STAGE = [&](int buf, int t) {
#pragma unroll
    for (int c = 0; c < CA; ++c) gload16(srcA[c] + t * 64, ldsA[c] + buf * TM * 64);
#pragma unroll
    for (int c = 0; c < CB; ++c) gload16(srcB[c] + t * 64, ldsB[c] + buf * TN * 64);
  };

  STAGE(0, 0);
  STAGE(1, 1);
  for (int t = 0; t < nt; ++t) {
    if (t < nt - 1) { if constexpr (SN == 6) VWAIT(6); else VWAIT(4); }
    else VWAIT(0);
    bar();
    if (t + 2 < nt) STAGE((t + 2) % 3, t + 2);
    const int buf = t % 3;
#pragma unroll
    for (int ks = 0; ks < 2; ++ks) {
      const int kb = ks * 64 + ((lane >> 4) << 4);
      bf16x8 af[WM], bfr[WN];
#pragma unroll
      for (int f = 0; f < WM; ++f) {
        int ra = wm * (TM / 2) + f * 16 + (lane & 15);
        af[f] = *(const bf16x8*)((const char*)As + buf * TM * 128 + ra * 128 + (kb ^ ((ra & 7) << 4)));
      }
#pragma unroll
      for (int g = 0; g < WN; ++g) {
        int rb = wn * (TN / 2) + g * 16 + (lane & 15);
        bfr[g] = *(const bf16x8*)((const char*)Bs + buf * TN * 128 + rb * 128 + (kb ^ ((rb & 7) << 4)));
      }
      __builtin_amdgcn_s_setprio(1);
#pragma unroll
      for (int i = 0; i < WM; ++i)
#pragma unroll
        for (int j = 0; j < WN; ++j)
          acc[i][j] = __builtin_amdgcn_mfma_f32_16x16x32_bf16(af[i], bfr[j], acc[i][j], 0, 0, 0);
      __builtin_amdgcn_s_setprio(0);
    }
  }

  const int row0 = blockIdx.y * TM + wm * (TM / 2) + ((lane >> 4) << 2);
  int col0 = blockIdx.x * TN + wn * (TN / 2) + (lane & 15);
  const float* bsel = bias;
  ushort_t* osel = outB;
  int seg = 0;
  if (EPI == 3) {
    seg = (blockIdx.x * TN) >> 11;
    if (seg == 1) { bsel = bias2; osel = outB2; }
    else if (seg == 2) { bsel = bias3; }
    col0 -= seg * 2048;
  }

  if (EPI == 3 && seg == 2) {
    // V segment: repack 128(row) x 64(col) tile via LDS, write vT[bh][dk][s]
    ushort_t* Vt = As;              // reuse staging LDS (padded stride 136)
    bar();                          // all waves done reading As
#pragma unroll
    for (int i = 0; i < WM; ++i)
#pragma unroll
      for (int j = 0; j < WN; ++j) {
        const int colL = wn * (TN / 2) + j * 16 + (lane & 15);
        const float bv = bsel[(col0 + j * 16) & 2047];
#pragma unroll
        for (int r = 0; r < 4; ++r) {
          const int rowL = wm * (TM / 2) + i * 16 + ((lane >> 4) << 2) + r;
          Vt[colL * 136 + rowL] = f2b(acc[i][j][r] + bv);
        }
      }
    bar();
    const int colvBase = blockIdx.x * TN - 4096;         // within V's 2048 cols
    const int h = colvBase >> 8, dk0 = colvBase & 255;
    const int rowBase = blockIdx.y * TM;
    const int bh = ((rowBase >> 8) << 3) + h;
    const int s0 = rowBase & 255;
    const int dkl = tid >> 2, scc = (tid & 3) * 32;
    ushort_t* dst = outB3 + ((long)bh << 16) + (long)(dk0 + dkl) * 256 + s0 + scc;
#pragma unroll
    for (int m = 0; m < 4; ++m)
      *(u16x8*)(dst + m * 8) = *(const u16x8*)(Vt + dkl * 136 + scc + m * 8);
    return;
  }

#pragma unroll
  for (int i = 0; i < WM; ++i) {
#pragma unroll
    for (int j = 0; j < WN; ++j) {
      const int col = col0 + j * 16;
      float bv;
      if (EPI == 2) bv = (kz == 0) ? bias[col] : 0.f;
      else          bv = bsel[col];
#pragma unroll
      for (int r = 0; r < 4; ++r) {
        const int row = row0 + i * 16 + r;
        float v = acc[i][j][r] + bv;
        if (EPI == 2) {
          outF[(long)kz * 1048576 + (long)row * ldc + col] = v;
        } else {
          if (relu) v = fmaxf(v, 0.f);
          osel[(long)row * ldc + col] = f2b(v);
        }
      }
    }
  }
}

// ---------------------------------------------------------------------------
// Fused flash attention, counted-vmcnt pipeline, depth-2 prefetch.
// Block: (q-tile of 64, b*8+h). Qs (32KB) reused as P after QK phase.
// ---------------------------------------------------------------------------
__global__ __launch_bounds__(256)
void attn_k(const ushort_t* __restrict__ qb, const ushort_t* __restrict__ kbf,
            const ushort_t* __restrict__ vT, const int* __restrict__ attnm,
            ushort_t* __restrict__ ao)
{
  __shared__ ushort_t Qs[64 * 256];        // 32KB; becomes P after QK
  __shared__ ushort_t KV[3][64 * 256];     // 96KB
  __shared__ int smask[256];
  const int qt = blockIdx.x, bh = blockIdx.y, b = bh >> 3, h = bh & 7;
  const int tid = threadIdx.x, lane = tid & 63, wid = tid >> 6;

  smask[tid] = attnm[b * 256 + tid];
  VWAIT(0);   // drain mask load so stage counting is exact

  int srow[8], scol[8];
#pragma unroll
  for (int c = 0; c < 8; ++c) {
    int off = c * 4096 + tid * 16;
    srow[c] = off >> 9;
    scol[c] = ((off & 511) ^ ((srow[c] & 7) << 4)) >> 1;
  }

#define STQ() do { _Pragma("unroll") for (int c = 0; c < 8; ++c) \
  gload16(qb + (long)(b * 256 + qt * 64 + srow[c]) * 2048 + h * 256 + scol[c], Qs + c * 2048 + wid * 512); } while (0)
#define STK(KC, DST) do { _Pragma("unroll") for (int c = 0; c < 8; ++c) \
  gload16(kbf + (long)(b * 256 + (KC) * 64 + srow[c]) * 2048 + h * 256 + scol[c], (DST) + c * 2048 + wid * 512); } while (0)
#define STV(VC, DST) do { _Pragma("unroll") for (int c = 0; c < 8; ++c) \
  gload16(vT + ((long)bh << 16) + (long)((VC) * 64 + srow[c]) * 256 + scol[c], (DST) + c * 2048 + wid * 512); } while (0)

  f32x4 accs[16] = {};
  f32x4 acco[4][4] = {};

#define QKC(IDX, KVB) do { __builtin_amdgcn_s_setprio(1); _Pragma("unroll") \
  for (int ks = 0; ks < 8; ++ks) { \
    const int kb = ks * 64 + ((lane >> 4) << 4); \
    const int ra = wid * 16 + (lane & 15); \
    bf16x8 aq = *(const bf16x8*)((const char*)Qs + ra * 512 + (kb ^ ((ra & 7) << 4))); \
    _Pragma("unroll") \
    for (int j = 0; j < 4; ++j) { \
      const int rb = j * 16 + (lane & 15); \
      bf16x8 bk_ = *(const bf16x8*)((const char*)(KVB) + rb * 512 + (kb ^ ((rb & 7) << 4))); \
      accs[(IDX) * 4 + j] = __builtin_amdgcn_mfma_f32_16x16x32_bf16(aq, bk_, accs[(IDX) * 4 + j], 0, 0, 0); \
    } \
  } __builtin_amdgcn_s_setprio(0); } while (0)

#define PVC(VC, KVB) do { __builtin_amdgcn_s_setprio(1); _Pragma("unroll") \
  for (int ks = 0; ks < 8; ++ks) { \
    const int kb = ks * 64 + ((lane >> 4) << 4); \
    const int ra = wid * 16 + (lane & 15); \
    bf16x8 pa = *(const bf16x8*)((const char*)Qs + ra * 512 + (kb ^ ((ra & 7) << 4))); \
    _Pragma("unroll") \
    for (int j = 0; j < 4; ++j) { \
      const int rb = j * 16 + (lane & 15); \
      bf16x8 bv_ = *(const bf16x8*)((const char*)(KVB) + rb * 512 + (kb ^ ((rb & 7) << 4))); \
      acco[VC][j] = __builtin_amdgcn_mfma_f32_16x16x32_bf16(pa, bv_, acco[VC][j], 0, 0, 0); \
    } \
  } __builtin_amdgcn_s_setprio(0); } while (0)

  // prologue: Q, K0, K1 in flight (24)
  STQ(); STK(0, KV[0]); STK(1, KV[1]);

  VWAIT(16); bar(); STK(2, KV[2]); QKC(0, KV[0]);   // wait Q,K0
  VWAIT(8);  bar(); STK(3, KV[0]); QKC(1, KV[1]);   // wait K1
  VWAIT(8);  bar(); STV(0, KV[1]); QKC(2, KV[2]);   // wait K2
  VWAIT(8);  bar(); STV(1, KV[2]); QKC(3, KV[0]);   // wait K3

  bar();              // all waves done with Qs(Q) and KV[0](K3)
  STV(2, KV[0]);      // outstanding: V0,V1,V2 = 24

  // softmax over 256 keys per q-row; lane holds 16 cols x 4 rows
  {
    float mr[4] = {-3e38f, -3e38f, -3e38f, -3e38f}, sr[4] = {};
#pragma unroll
    for (int jj = 0; jj < 16; ++jj) {
      int key = jj * 16 + (lane & 15);
      bool mk = smask[key] != 0;
#pragma unroll
      for (int r = 0; r < 4; ++r) {
        float s = mk ? -1e9f : accs[jj][r] * 0.0625f;
        accs[jj][r] = s;
        mr[r] = fmaxf(mr[r], s);
      }
    }
#pragma unroll
    for (int o = 1; o < 16; o <<= 1)
#pragma unroll
      for (int r = 0; r < 4; ++r) mr[r] = fmaxf(mr[r], __shfl_xor(mr[r], o, 64));
#pragma unroll
    for (int jj = 0; jj < 16; ++jj)
#pragma unroll
      for (int r = 0; r < 4; ++r) {
        float e = __expf(accs[jj][r] - mr[r]);
        accs[jj][r] = e;
        sr[r] += e;
      }
#pragma unroll
    for (int o = 1; o < 16; o <<= 1)
#pragma unroll
      for (int r = 0; r < 4; ++r) sr[r] += __shfl_xor(sr[r], o, 64);
#pragma unroll
    for (int r = 0; r < 4; ++r) sr[r] = 1.f / sr[r];
    // P -> Qs (own wave's rows only; no barrier needed)
#pragma unroll
    for (int jj = 0; jj < 16; ++jj)
#pragma unroll
      for (int r = 0; r < 4; ++r) {
        int prow = wid * 16 + ((lane >> 4) << 2) + r;
        int cb = (jj * 16 + (lane & 15)) * 2;
        *(ushort_t*)((char*)Qs + prow * 512 + (cb ^ ((prow & 7) << 4))) = f2b(accs[jj][r] * sr[r]);
      }
  }

  VWAIT(16); bar();                 PVC(0, KV[1]);  // wait V0
  VWAIT(8);  bar(); STV(3, KV[1]); PVC(1, KV[2]);   // wait V1
  VWAIT(8);  bar();                 PVC(2, KV[0]);  // wait V2
  VWAIT(0);  bar();                 PVC(3, KV[1]);  // wait V3

#pragma unroll
  for (int vc = 0; vc < 4; ++vc)
#pragma unroll
    for (int j = 0; j < 4; ++j)
#pragma unroll
      for (int r = 0; r < 4; ++r) {
        int q = qt * 64 + wid * 16 + ((lane >> 4) << 2) + r;
        int dk = vc * 64 + j * 16 + (lane & 15);
        ao[(long)(b * 256 + q) * 2048 + h * 256 + dk] = f2b(acco[vc][j][r]);
      }
#undef STQ
#undef STK
#undef STV
#undef QKC
#undef PVC
}

// x = data*sqrt(D) + pe + seg_emb[view_idx*S]
__global__ __launch_bounds__(256)
void build_x(const float* __restrict__ data, const float* __restrict__ seg,
             const int* __restrict__ viewp, float* __restrict__ x)
{
  int i = blockIdx.x * 256 + threadIdx.x;
  int d = i & 511;
  int s = (i >> 9) & 255;
  float ang = (float)s * exp2f((float)d * -0.03125f);
  float pe = (d & 1) ? cosf(ang) : sinf(ang);
  int vrow = viewp[0] * SS;
  x[i] = data[i] * 22.627416997969522f + pe + seg[vrow * DIM + d];
}

// LayerNorm with optional fused residual: x += sum(parts[0..np)), write back,
// then normalize (unbiased var, eps on std). outB: bf16 out; outF: fp32 out.
__global__ __launch_bounds__(256)
void lnorm_k(const float* __restrict__ x, const float* __restrict__ parts, int np,
             float* __restrict__ xout,
             const float* __restrict__ alpha, const float* __restrict__ beta,
             ushort_t* __restrict__ outB, float* __restrict__ outF)
{
  const int row = blockIdx.x, tid = threadIdx.x;
  const long base = (long)row * DIM;
  float2 v = ((const float2*)(x + base))[tid];
  if (np) {
    for (int p = 0; p < np; ++p) {
      float2 a = ((const float2*)(parts + (long)p * 1048576 + base))[tid];
      v.x += a.x; v.y += a.y;
    }
    ((float2*)(xout + base))[tid] = v;
  }
  float s = v.x + v.y;
#pragma unroll
  for (int o = 32; o; o >>= 1) s += __shfl_xor(s, o, 64);
  __shared__ float rs[4], rq[4];
  if ((tid & 63) == 0) rs[tid >> 6] = s;
  __syncthreads();
  const float mu = (rs[0] + rs[1] + rs[2] + rs[3]) * (1.f / 512.f);
  const float dx = v.x - mu, dy = v.y - mu;
  float q = dx * dx + dy * dy;
#pragma unroll
  for (int o = 32; o; o >>= 1) q += __shfl_xor(q, o, 64);
  if ((tid & 63) == 0) rq[tid >> 6] = q;
  __syncthreads();
  const float var = (rq[0] + rq[1] + rq[2] + rq[3]) * (1.f / 511.f);
  const float rstd = 1.f / (sqrtf(var) + 1e-6f);
  const int d0 = tid * 2;
  const float o0 = alpha[d0] * dx * rstd + beta[d0];
  const float o1 = alpha[d0 + 1] * dy * rstd + beta[d0 + 1];
  if (outB) { outB[base + d0] = f2b(o0); outB[base + d0 + 1] = f2b(o1); }
  else      { outF[base + d0] = o0;      outF[base + d0 + 1] = o1; }
}

// fp32 [R,C] -> bf16 [C,R], per-z with output z-stride (elements)
__global__ __launch_bounds__(256)
void wtrans(const float* __restrict__ in, ushort_t* __restrict__ out,
            int R, int C, long ozs)
{
  __shared__ float t[32][33];
  const int z = blockIdx.z;
  const long zi = (long)z * R * C, zo = (long)z * ozs;
  const int c0 = blockIdx.x * 32, r0 = blockIdx.y * 32;
  const int tx = threadIdx.x & 31, ty = threadIdx.x >> 5;
#pragma unroll
  for (int i = 0; i < 4; ++i) t[ty + i * 8][tx] = in[zi + (long)(r0 + ty + i * 8) * C + c0 + tx];
  __syncthreads();
#pragma unroll
  for (int i = 0; i < 4; ++i) out[zo + (long)(c0 + ty + i * 8) * R + r0 + tx] = f2b(t[tx][ty + i * 8]);
}

extern "C" void kernel_launch(void* const* d_in, const int* in_sizes, int n_in,
                              void* d_out, int out_size, void* d_ws, size_t ws_size,
                              hipStream_t stream)
{
  const float* data  = (const float*)d_in[0];
  const int*   attnm = (const int*)d_in[1];
  const int*   viewp = (const int*)d_in[2];
  const float* seg   = (const float*)d_in[3];
  const float* Wq    = (const float*)d_in[4];
  const float* bq    = (const float*)d_in[5];
  const float* Wk    = (const float*)d_in[6];
  const float* bk    = (const float*)d_in[7];
  const float* Wv    = (const float*)d_in[8];
  const float* bv    = (const float*)d_in[9];
  const float* Wo    = (const float*)d_in[10];
  const float* bo    = (const float*)d_in[11];
  const float* W1    = (const float*)d_in[12];
  const float* b1    = (const float*)d_in[13];
  const float* W2    = (const float*)d_in[14];
  const float* b2    = (const float*)d_in[15];
  const float* al1   = (const float*)d_in[16];
  const float* be1   = (const float*)d_in[17];
  const float* al2   = (const float*)d_in[18];
  const float* be2   = (const float*)d_in[19];
  const float* alf   = (const float*)d_in[20];
  const float* bef   = (const float*)d_in[21];

  char* w = (char*)d_ws;
  const size_t MB = 1024 * 1024;
  ushort_t* qkvW = (ushort_t*)(w + 0 * MB);   // [L][6144][512] bf16
  ushort_t* WoT  = (ushort_t*)(w + 24 * MB);  // [L][512][2048]
  ushort_t* W1T  = (ushort_t*)(w + 32 * MB);  // [L][2048][512]
  ushort_t* W2T  = (ushort_t*)(w + 40 * MB);  // [L][512][2048]
  float*    x    = (float*)   (w + 48 * MB);  // [2048][512] fp32
  ushort_t* x2   = (ushort_t*)(w + 52 * MB);  // [2048][512] bf16
  ushort_t* qb   = (ushort_t*)(w + 54 * MB);  // [2048][2048] bf16
  ushort_t* kbf  = (ushort_t*)(w + 62 * MB);
  ushort_t* vT   = (ushort_t*)(w + 70 * MB);  // [64][256][256]
  ushort_t* ao   = (ushort_t*)(w + 78 * MB);  // [2048][2048]
  ushort_t* ffh  = (ushort_t*)(w + 86 * MB);  // [2048][2048]
  float*    parts= (float*)   (w + 94 * MB);  // 4 x [2048][512] fp32 (94..110MB)

  dim3 blk(256);
  const long QKV_L = 6144L * 512;
  wtrans<<<dim3(64, 16, 4), blk, 0, stream>>>(Wq, qkvW + 0 * 2048 * 512, 512, 2048, QKV_L);
  wtrans<<<dim3(64, 16, 4), blk, 0, stream>>>(Wk, qkvW + 1 * 2048 * 512, 512, 2048, QKV_L);
  wtrans<<<dim3(64, 16, 4), blk, 0, stream>>>(Wv, qkvW + 2 * 2048 * 512, 512, 2048, QKV_L);
  wtrans<<<dim3(16, 64, 4), blk, 0, stream>>>(Wo, WoT, 2048, 512, 512L * 2048);
  wtrans<<<dim3(64, 16, 4), blk, 0, stream>>>(W1, W1T, 512, 2048, 2048L * 512);
  wtrans<<<dim3(16, 64, 4), blk, 0, stream>>>(W2, W2T, 2048, 512, 512L * 2048);
  build_x<<<4096, blk, 0, stream>>>(data, seg, viewp, x);

  for (int i = 0; i < LNUM; ++i) {
    if (i == 0)
      lnorm_k<<<2048, blk, 0, stream>>>(x, nullptr, 0, nullptr, al1, be1, x2, nullptr);
    // fused QKV: [2048,512] x [6144,512]^T ; V repacked via LDS to vT
    gemm_bt<128, 64, 3><<<dim3(96, 16, 1), blk, 0, stream>>>(
        x2, qkvW + (long)i * QKV_L, bq + i * 2048, bk + i * 2048, bv + i * 2048,
        qb, kbf, vT, nullptr, 512, 512, 512, 2048, 1, 0);
    attn_k<<<dim3(4, 64), blk, 0, stream>>>(qb, kbf, vT, attnm, ao);
    // Wo: [2048,2048] x [512,2048]^T, split-K=4 -> parts
    gemm_bt<64, 64, 2><<<dim3(8, 32, 4), blk, 0, stream>>>(
        ao, WoT + (long)i * 512 * 2048, bo + i * 512, nullptr, nullptr,
        nullptr, nullptr, nullptr, parts, 2048, 2048, 2048, 512, 4, 0);
    lnorm_k<<<2048, blk, 0, stream>>>(x, parts, 4, x, al2 + i * 512, be2 + i * 512, x2, nullptr);
    // FF1: [2048,512] x [2048,512]^T, relu
    gemm_bt<128, 64, 0><<<dim3(32, 16, 1), blk, 0, stream>>>(
        x2, W1T + (long)i * 2048 * 512, b1 + i * 2048, nullptr, nullptr,
        ffh, nullptr, nullptr, nullptr, 512, 512, 512, 2048, 1, 1);
    // FF2: [2048,2048] x [512,2048]^T, split-K=4 -> parts
    gemm_bt<64, 64, 2><<<dim3(8, 32, 4), blk, 0, stream>>>(
        ffh, W2T + (long)i * 512 * 2048, b2 + i * 512, nullptr, nullptr,
        nullptr, nullptr, nullptr, parts, 2048, 2048, 2048, 512, 4, 0);
    if (i < LNUM - 1)
      lnorm_k<<<2048, blk, 0, stream>>>(x, parts, 4, x, al1 + (i + 1) * 512, be1 + (i + 1) * 512, x2, nullptr);
    else
      lnorm_k<<<2048, blk, 0, stream>>>(x, parts, 4, x, alf, bef, nullptr, (float*)d_out);
  }
}